// Round 12
// baseline (39886.963 us; speedup 1.0000x reference)
//
#include <hip/hip_runtime.h>

#define SEQ    2048
#define BATCH  64
#define DIN    512
#define HID    512
#define GATES  2048
#define NBLK   256      // 8 XCD groups x 32 slots (1 block/CU, coop-resident)
#define NT     256      // 4 waves
#define TC     8        // x-projection chunk length
#define ZST    65       // zxb row stride (f32)

typedef short bf16v8 __attribute__((ext_vector_type(8)));
typedef float f32x4  __attribute__((ext_vector_type(4)));

static __device__ __forceinline__ unsigned short f2bfbits(float f) {
    union { __bf16 h; unsigned short s; } u;
    u.h = (__bf16)f;           // RNE
    return u.s;
}

static __device__ __forceinline__ bf16v8 cvt8(const float* __restrict__ p) {
    float4 a = *(const float4*)(p);
    float4 b = *(const float4*)(p + 4);
    union { __bf16 h[8]; bf16v8 v; } u;
    u.h[0] = (__bf16)a.x; u.h[1] = (__bf16)a.y;
    u.h[2] = (__bf16)a.z; u.h[3] = (__bf16)a.w;
    u.h[4] = (__bf16)b.x; u.h[5] = (__bf16)b.y;
    u.h[6] = (__bf16)b.z; u.h[7] = (__bf16)b.w;
    return u.v;
}

static __device__ __forceinline__ float sigm(float v) {
    return 1.0f / (1.0f + __expf(-v));
}
static __device__ __forceinline__ float ftanh(float v) {
    return 1.0f - 2.0f / (__expf(2.0f * v) + 1.0f);
}

// ===== v11: v10 topology + BUSY-POLL (clock-throttle countermeasure) ========
// v10 showed step time (~14us) invariant to sync mechanism while traffic
// varied 80x -> hypothesis: 95%-stalled kernel drops SCLK to its floor.
// v11 keeps v10 byte-identical EXCEPT: all 4 waves busy-poll the step flags
// with a dependent FMA burn chain (no s_sleep, no idle barrier wait), keeping
// VALUBusy high so the DPM governor holds clocks up.
__global__ void __launch_bounds__(NT, 1) lstm_v11(
    const float* __restrict__ x,  const float* __restrict__ c0,
    const float* __restrict__ h0, const float* __restrict__ Wi,
    const float* __restrict__ Wh, const float* __restrict__ bias,
    float* __restrict__ out, unsigned int* flags, unsigned int* mall,
    unsigned int* claim, unsigned short* hglob)
{
    __shared__ unsigned short wi_lds[64 * 512];   // 64 KB
    __shared__ unsigned short wh_lds[64 * 512];   // 64 KB
    __shared__ float zxb[64 * ZST];               // 16.25 KB
    __shared__ unsigned short h_lds[8 * 512];     // 8 KB, swizzled
    __shared__ float ys_lds[TC * 8 * 16];         // 4 KB
    __shared__ int xs_lds[2];
    __shared__ int abortf;

    const int tid  = threadIdx.x;
    const int lane = tid & 63;
    const int wv   = tid >> 6;
    const int col  = lane & 15;
    const int rgrp = lane >> 4;
    const int c7   = col & 7;
    const int c3   = col & 3;

    // ---- claim role from actual placement ----
    unsigned int xcd;
    asm volatile("s_getreg_b32 %0, hwreg(HW_REG_XCC_ID)" : "=s"(xcd));
    if (tid == 0) {
        abortf = 0;
        unsigned int slot = __hip_atomic_fetch_add(&claim[(xcd & 7) * 16], 1u,
                               __ATOMIC_RELAXED, __HIP_MEMORY_SCOPE_AGENT);
        xs_lds[0] = (int)(xcd & 7);
        xs_lds[1] = (int)(slot & 31);
    }
    __syncthreads();
    const int x_ = xs_lds[0];
    const int s_ = xs_lds[1];

    // ---- weights: 64 gate cols; lc = w*16 + type*4 + jj -> hidden 16s+4w+jj
    for (int idx = tid; idx < 64 * 512; idx += NT) {
        const int lc = idx & 63, k = idx >> 6;
        const int c = lc & 15, w = lc >> 4;
        const int gc = (c >> 2) * HID + s_ * 16 + w * 4 + (c & 3);
        const int sidx = lc * 512 + ((((k >> 3) ^ (c & 7)) << 3) | (k & 7));
        wi_lds[sidx] = f2bfbits(Wi[(size_t)k * GATES + gc]);
        wh_lds[sidx] = f2bfbits(Wh[(size_t)k * GATES + gc]);
    }

    // clean own flag in the local L2 (stale-line fix across graph replays)
    if (tid == 0)
        (void)__hip_atomic_exchange(&flags[(x_ * 32 + s_) * 16], 0u,
                                    __ATOMIC_RELAXED,
                                    __HIP_MEMORY_SCOPE_WORKGROUP);

    // seed h_0 slice into buf 0 (plain write-through stores)
    if (tid < 128) {
        const int row = tid >> 4, j = tid & 15;
        hglob[(x_ * 8 + row) * 512 + s_ * 16 + j] =
            f2bfbits(h0[(8 * x_ + row) * HID + s_ * 16 + j]);
    }
    asm volatile("s_waitcnt vmcnt(0)" ::: "memory");
    __syncthreads();

    // one-time MALL rendezvous (proven agent-atomic pattern), watchdogged
    if (tid == 0)
        __hip_atomic_store(&mall[(x_ * 32 + s_) * 16], 1u,
                           __ATOMIC_RELAXED, __HIP_MEMORY_SCOPE_AGENT);
    if (wv == 0) {
        int guard = 0;
        unsigned int v;
        do {
            v = __hip_atomic_load(&mall[(x_ * 32 + (lane & 31)) * 16],
                                  __ATOMIC_RELAXED, __HIP_MEMORY_SCOPE_AGENT);
            if (__all(v >= 1u)) break;
            __builtin_amdgcn_s_sleep(8);
        } while (++guard < (1 << 20));
        if (guard >= (1 << 20)) abortf = 1;
    }
    __syncthreads();
    if (tid == 0)
        __hip_atomic_store(&flags[(x_ * 32 + s_) * 16], 1u,
                           __ATOMIC_RELAXED, __HIP_MEMORY_SCOPE_WORKGROUP);

    // ---- hoist Wh fragments (loop-invariant; 1 wave/SIMD so VGPRs free)
    bf16v8 whf[16];
    #pragma unroll
    for (int ks = 0; ks < 16; ++ks)
        whf[ks] = *(const bf16v8*)(wh_lds + (wv * 16 + col) * 512 +
                                   (((ks * 4 + rgrp) ^ c7) << 3));

    float bvA[4];
    #pragma unroll
    for (int g = 0; g < 4; ++g)
        bvA[g] = bias[(col >> 2) * HID + s_ * 16 + g * 4 + c3];

    const int hcol = s_ * 16 + 4 * wv + col;
    const bool act = (col < 4) && (rgrp < 2);
    float cv[4];
    #pragma unroll
    for (int r = 0; r < 4; ++r)
        cv[r] = act ? c0[(8 * x_ + rgrp * 4 + r) * HID + hcol] : 0.0f;

    for (int t0 = 0; t0 < SEQ; t0 += TC) {
        // ---- flush previous chunk's ys (off the critical path) ----
        if (t0 > 0) {
            const int ft = tid >> 5, fr = (tid >> 2) & 7, fc = (tid & 3) * 4;
            const float4 v = *(const float4*)(ys_lds + (ft * 8 + fr) * 16 + fc);
            *(float4*)(out + 2 * (size_t)BATCH * HID +
                       ((size_t)(t0 - TC + ft) * BATCH + 8 * x_ + fr) * HID +
                       s_ * 16 + fc) = v;
        }

        // ---- phase A: wave wv -> zxb rows [16wv,16wv+16) x 64 cols ----
        {
            f32x4 za0 = {0,0,0,0}, za1 = {0,0,0,0}, za2 = {0,0,0,0}, za3 = {0,0,0,0};
            const int rr = wv * 16 + col;
            const float* xrow = x + ((size_t)(t0 + (rr >> 3)) * BATCH +
                                     8 * x_ + (rr & 7)) * DIN;
            #pragma unroll
            for (int ks = 0; ks < 16; ++ks) {
                const bf16v8 axv = cvt8(xrow + ks * 32 + rgrp * 8);
                const int gsw = ((ks * 4 + rgrp) ^ c7) << 3;
                const bf16v8 b0 = *(const bf16v8*)(wi_lds + (col) * 512 + gsw);
                const bf16v8 b1 = *(const bf16v8*)(wi_lds + (16 + col) * 512 + gsw);
                const bf16v8 b2 = *(const bf16v8*)(wi_lds + (32 + col) * 512 + gsw);
                const bf16v8 b3 = *(const bf16v8*)(wi_lds + (48 + col) * 512 + gsw);
                za0 = __builtin_amdgcn_mfma_f32_16x16x32_bf16(axv, b0, za0, 0, 0, 0);
                za1 = __builtin_amdgcn_mfma_f32_16x16x32_bf16(axv, b1, za1, 0, 0, 0);
                za2 = __builtin_amdgcn_mfma_f32_16x16x32_bf16(axv, b2, za2, 0, 0, 0);
                za3 = __builtin_amdgcn_mfma_f32_16x16x32_bf16(axv, b3, za3, 0, 0, 0);
            }
            #pragma unroll
            for (int r = 0; r < 4; ++r) {
                const int zr = (wv * 16 + rgrp * 4 + r) * ZST;
                zxb[zr + col]      = za0[r] + bvA[0];
                zxb[zr + 16 + col] = za1[r] + bvA[1];
                zxb[zr + 32 + col] = za2[r] + bvA[2];
                zxb[zr + 48 + col] = za3[r] + bvA[3];
            }
        }
        __syncthreads();

        // ---- phase B: recurrence ----
        for (int tt = 0; tt < TC; ++tt) {
            const int t = t0 + tt;

            // poll group flags >= t+1: ALL WAVES busy-poll with FMA burn.
            // The burn keeps VALUBusy (and thus SCLK) high; laundered so it
            // can't be optimized out. Watchdogged as before.
            if (!abortf) {
                const unsigned int tgt = (unsigned int)t + 1u;
                const unsigned int* fp = &flags[(x_ * 32 + (lane & 31)) * 16];
                int guard = 0;
                float burn = 1.0f + (float)lane * 1e-6f;
                while (true) {
                    __builtin_amdgcn_fence(__ATOMIC_ACQUIRE, "agent");
                    const unsigned int v = *(const volatile unsigned int*)fp;
                    if (__all(v >= tgt)) break;
                    if (++guard > (1 << 22)) { abortf = 1; break; }
                    #pragma unroll
                    for (int i = 0; i < 64; ++i)
                        burn = __builtin_fmaf(burn, 1.0000001f, 1e-9f);
                    asm volatile("" : "+v"(burn));
                }
            }
            __syncthreads();

            // stage h_t (buf t&1) -> h_lds: fence + PLAIN 16B loads (L2-hit)
            {
                __builtin_amdgcn_fence(__ATOMIC_ACQUIRE, "agent");
                const int row = tid >> 5, ks2 = (tid >> 1) & 15, rg0 = (tid & 1) * 2;
                const unsigned long long* src = (const unsigned long long*)
                    (hglob + (((t & 1) * 8 + x_) * 8 + row) * 512)
                    + (ks2 * 8 + rg0 * 2);
                const unsigned long long q0 = src[0];
                const unsigned long long q1 = src[1];
                const unsigned long long q2 = src[2];
                const unsigned long long q3 = src[3];
                const int base = row * 512 + ks2 * 32;
                unsigned long long* d0 = (unsigned long long*)
                    (h_lds + base + ((rg0 ^ (row & 3)) << 3));
                d0[0] = q0; d0[1] = q1;
                unsigned long long* d1 = (unsigned long long*)
                    (h_lds + base + (((rg0 + 1) ^ (row & 3)) << 3));
                d1[0] = q2; d1[1] = q3;
            }
            __syncthreads();

            // z = zxb(+bias) + h @ Wh
            f32x4 accA, accB = {0, 0, 0, 0};
            {
                const int zr = (tt * 8 + (rgrp & 1) * 4) * ZST + wv * 16 + col;
                accA[0] = zxb[zr];           accA[1] = zxb[zr + ZST];
                accA[2] = zxb[zr + 2 * ZST]; accA[3] = zxb[zr + 3 * ZST];
            }
            const int abase = (col & 7) * 512 + ((rgrp ^ c3) << 3);
            #pragma unroll
            for (int ks = 0; ks < 16; ks += 2) {
                const bf16v8 a0 = *(const bf16v8*)(h_lds + abase + ks * 32);
                const bf16v8 a1 = *(const bf16v8*)(h_lds + abase + ks * 32 + 32);
                accA = __builtin_amdgcn_mfma_f32_16x16x32_bf16(a0, whf[ks],     accA, 0, 0, 0);
                accB = __builtin_amdgcn_mfma_f32_16x16x32_bf16(a1, whf[ks + 1], accB, 0, 0, 0);
            }

            float z[4], zf[4], zg[4], zo[4];
            #pragma unroll
            for (int r = 0; r < 4; ++r) z[r] = accA[r] + accB[r];
            #pragma unroll
            for (int r = 0; r < 4; ++r) {
                zf[r] = __shfl_xor(z[r], 4);    // f gate
                zg[r] = __shfl_xor(z[r], 8);    // g gate
                zo[r] = __shfl_xor(z[r], 12);   // o gate
            }

            if (act) {
                #pragma unroll
                for (int r = 0; r < 4; ++r) {
                    const float ig = sigm(z[r]);
                    const float fg = sigm(zf[r]);
                    const float gg = ftanh(zg[r]);
                    const float og = sigm(zo[r]);
                    const float cn = fg * cv[r] + ig * gg;
                    cv[r] = cn;
                    const float hn = og * ftanh(cn);
                    const int row = rgrp * 4 + r;
                    hglob[((((t + 1) & 1) * 8 + x_) * 8 + row) * 512 + hcol] =
                        f2bfbits(hn);                          // plain, write-through
                    ys_lds[(tt * 8 + row) * 16 + 4 * wv + col] = hn;
                    if (t == SEQ - 1) {
                        out[(size_t)(8 * x_ + row) * HID + hcol] = cn;                    // cT
                        out[(size_t)BATCH * HID + (size_t)(8 * x_ + row) * HID + hcol] = hn; // hT
                    }
                }
            }
            // drain ALL waves' h stores to L2, then publish
            asm volatile("s_waitcnt vmcnt(0)" ::: "memory");
            __syncthreads();
            if (tid == 0)
                __hip_atomic_store(&flags[(x_ * 32 + s_) * 16],
                                   (unsigned int)t + 2u,
                                   __ATOMIC_RELAXED,
                                   __HIP_MEMORY_SCOPE_WORKGROUP);
        }
    }

    // ---- final ys flush ----
    __syncthreads();
    {
        const int ft = tid >> 5, fr = (tid >> 2) & 7, fc = (tid & 3) * 4;
        const float4 v = *(const float4*)(ys_lds + (ft * 8 + fr) * 16 + fc);
        *(float4*)(out + 2 * (size_t)BATCH * HID +
                   ((size_t)(SEQ - TC + ft) * BATCH + 8 * x_ + fr) * HID +
                   s_ * 16 + fc) = v;
    }
}

extern "C" void kernel_launch(void* const* d_in, const int* in_sizes, int n_in,
                              void* d_out, int out_size, void* d_ws, size_t ws_size,
                              hipStream_t stream) {
    const float* x  = (const float*)d_in[0];
    const float* c0 = (const float*)d_in[1];
    const float* h0 = (const float*)d_in[2];
    const float* Wi = (const float*)d_in[3];
    const float* Wh = (const float*)d_in[4];
    const float* b  = (const float*)d_in[5];
    float* out = (float*)d_out;

    // ws: [0,16K) flags | [16K,32K) MALL rendezvous | [32K,+512) claim
    //     [36864, +128K) h double buffer [2][8 xcd][8 row][512] bf16
    char* wsb = (char*)d_ws;
    unsigned int* flags   = (unsigned int*)wsb;
    unsigned int* mall    = (unsigned int*)(wsb + 16384);
    unsigned int* claim   = (unsigned int*)(wsb + 32768);
    unsigned short* hglob = (unsigned short*)(wsb + 36864);

    (void)hipMemsetAsync(wsb, 0, 33280, stream);   // flags + mall + claim

    void* args[] = { (void*)&x, (void*)&c0, (void*)&h0, (void*)&Wi,
                     (void*)&Wh, (void*)&b, (void*)&out, (void*)&flags,
                     (void*)&mall, (void*)&claim, (void*)&hglob };
    (void)hipLaunchCooperativeKernel((void*)lstm_v11, dim3(NBLK), dim3(NT),
                                     args, 0, stream);
}

// Round 13
// 22216.322 us; speedup vs baseline: 1.7954x; 1.7954x over previous
//
#include <hip/hip_runtime.h>

#define SEQ    2048
#define BATCH  64
#define DIN    512
#define HID    512
#define GATES  2048
#define NBLK   256      // 8 XCD groups x 32 slots (1 block/CU, coop-resident)
#define NT     256      // 4 waves
#define TC     8        // x-projection chunk length
#define ZST    65       // zxb row stride (f32)

typedef short bf16v8 __attribute__((ext_vector_type(8)));
typedef float f32x4  __attribute__((ext_vector_type(4)));

static __device__ __forceinline__ unsigned short f2bfbits(float f) {
    union { __bf16 h; unsigned short s; } u;
    u.h = (__bf16)f;           // RNE
    return u.s;
}

static __device__ __forceinline__ bf16v8 cvt8(const float* __restrict__ p) {
    float4 a = *(const float4*)(p);
    float4 b = *(const float4*)(p + 4);
    union { __bf16 h[8]; bf16v8 v; } u;
    u.h[0] = (__bf16)a.x; u.h[1] = (__bf16)a.y;
    u.h[2] = (__bf16)a.z; u.h[3] = (__bf16)a.w;
    u.h[4] = (__bf16)b.x; u.h[5] = (__bf16)b.y;
    u.h[6] = (__bf16)b.z; u.h[7] = (__bf16)b.w;
    return u.v;
}

static __device__ __forceinline__ float sigm(float v) {
    return 1.0f / (1.0f + __expf(-v));
}
static __device__ __forceinline__ float ftanh(float v) {
    return 1.0f - 2.0f / (__expf(2.0f * v) + 1.0f);
}

// ====== v12: v10 topology; publish = L2-executing exchange + drain; =========
// ====== poll = fence-free +0 RMW (no sleep, no buffer_inv thrash)   =========
// Diagnosis chain: v9 (RMW staging) == v10 (fence staging) == ~14.5us/step,
// v11 (all-wave fence+burn poll) WORSE with VALUBusy DOWN -> waves stall on
// memory waits, not spin; suspect = flag publish lingering in the CU store
// buffer (plain store, never drained). v12 forces the publish to the L2 via
// atomic exchange and waits it out; pollers use cheap L2-executing RMWs.
__global__ void __launch_bounds__(NT, 1) lstm_v12(
    const float* __restrict__ x,  const float* __restrict__ c0,
    const float* __restrict__ h0, const float* __restrict__ Wi,
    const float* __restrict__ Wh, const float* __restrict__ bias,
    float* __restrict__ out, unsigned int* flags, unsigned int* mall,
    unsigned int* claim, unsigned short* hglob)
{
    __shared__ unsigned short wi_lds[64 * 512];   // 64 KB
    __shared__ unsigned short wh_lds[64 * 512];   // 64 KB
    __shared__ float zxb[64 * ZST];               // 16.25 KB
    __shared__ unsigned short h_lds[8 * 512];     // 8 KB, swizzled
    __shared__ float ys_lds[TC * 8 * 16];         // 4 KB
    __shared__ int xs_lds[2];
    __shared__ int abortf;

    const int tid  = threadIdx.x;
    const int lane = tid & 63;
    const int wv   = tid >> 6;
    const int col  = lane & 15;
    const int rgrp = lane >> 4;
    const int c7   = col & 7;
    const int c3   = col & 3;

    // laundered zero: keeps fetch_add(+0) a real RMW (L2-executing)
    unsigned int zu = 0; asm volatile("" : "+v"(zu));

    // ---- claim role from actual placement ----
    unsigned int xcd;
    asm volatile("s_getreg_b32 %0, hwreg(HW_REG_XCC_ID)" : "=s"(xcd));
    if (tid == 0) {
        abortf = 0;
        unsigned int slot = __hip_atomic_fetch_add(&claim[(xcd & 7) * 16], 1u,
                               __ATOMIC_RELAXED, __HIP_MEMORY_SCOPE_AGENT);
        xs_lds[0] = (int)(xcd & 7);
        xs_lds[1] = (int)(slot & 31);
    }
    __syncthreads();
    const int x_ = xs_lds[0];
    const int s_ = xs_lds[1];

    // ---- weights: 64 gate cols; lc = w*16 + type*4 + jj -> hidden 16s+4w+jj
    for (int idx = tid; idx < 64 * 512; idx += NT) {
        const int lc = idx & 63, k = idx >> 6;
        const int c = lc & 15, w = lc >> 4;
        const int gc = (c >> 2) * HID + s_ * 16 + w * 4 + (c & 3);
        const int sidx = lc * 512 + ((((k >> 3) ^ (c & 7)) << 3) | (k & 7));
        wi_lds[sidx] = f2bfbits(Wi[(size_t)k * GATES + gc]);
        wh_lds[sidx] = f2bfbits(Wh[(size_t)k * GATES + gc]);
    }

    // clean own flag in the local L2 (stale-line fix across graph replays)
    if (tid == 0)
        (void)__hip_atomic_exchange(&flags[(x_ * 32 + s_) * 16], 0u,
                                    __ATOMIC_RELAXED,
                                    __HIP_MEMORY_SCOPE_WORKGROUP);

    // seed h_0 slice into buf 0 (plain write-through stores)
    if (tid < 128) {
        const int row = tid >> 4, j = tid & 15;
        hglob[(x_ * 8 + row) * 512 + s_ * 16 + j] =
            f2bfbits(h0[(8 * x_ + row) * HID + s_ * 16 + j]);
    }
    asm volatile("s_waitcnt vmcnt(0)" ::: "memory");
    __syncthreads();

    // one-time MALL rendezvous (proven agent-atomic pattern), watchdogged
    if (tid == 0)
        __hip_atomic_store(&mall[(x_ * 32 + s_) * 16], 1u,
                           __ATOMIC_RELAXED, __HIP_MEMORY_SCOPE_AGENT);
    if (wv == 0) {
        int guard = 0;
        unsigned int v;
        do {
            v = __hip_atomic_load(&mall[(x_ * 32 + (lane & 31)) * 16],
                                  __ATOMIC_RELAXED, __HIP_MEMORY_SCOPE_AGENT);
            if (__all(v >= 1u)) break;
            __builtin_amdgcn_s_sleep(8);
        } while (++guard < (1 << 20));
        if (guard >= (1 << 20)) abortf = 1;
    }
    __syncthreads();
    if (tid == 0) {
        (void)__hip_atomic_exchange(&flags[(x_ * 32 + s_) * 16], 1u,
                                    __ATOMIC_RELAXED,
                                    __HIP_MEMORY_SCOPE_WORKGROUP);
        asm volatile("s_waitcnt vmcnt(0)" ::: "memory");
    }

    // ---- hoist Wh fragments (loop-invariant; 1 wave/SIMD so VGPRs free)
    bf16v8 whf[16];
    #pragma unroll
    for (int ks = 0; ks < 16; ++ks)
        whf[ks] = *(const bf16v8*)(wh_lds + (wv * 16 + col) * 512 +
                                   (((ks * 4 + rgrp) ^ c7) << 3));

    float bvA[4];
    #pragma unroll
    for (int g = 0; g < 4; ++g)
        bvA[g] = bias[(col >> 2) * HID + s_ * 16 + g * 4 + c3];

    const int hcol = s_ * 16 + 4 * wv + col;
    const bool act = (col < 4) && (rgrp < 2);
    float cv[4];
    #pragma unroll
    for (int r = 0; r < 4; ++r)
        cv[r] = act ? c0[(8 * x_ + rgrp * 4 + r) * HID + hcol] : 0.0f;

    for (int t0 = 0; t0 < SEQ; t0 += TC) {
        // ---- flush previous chunk's ys (off the critical path) ----
        if (t0 > 0) {
            const int ft = tid >> 5, fr = (tid >> 2) & 7, fc = (tid & 3) * 4;
            const float4 v = *(const float4*)(ys_lds + (ft * 8 + fr) * 16 + fc);
            *(float4*)(out + 2 * (size_t)BATCH * HID +
                       ((size_t)(t0 - TC + ft) * BATCH + 8 * x_ + fr) * HID +
                       s_ * 16 + fc) = v;
        }

        // ---- phase A: wave wv -> zxb rows [16wv,16wv+16) x 64 cols ----
        {
            f32x4 za0 = {0,0,0,0}, za1 = {0,0,0,0}, za2 = {0,0,0,0}, za3 = {0,0,0,0};
            const int rr = wv * 16 + col;
            const float* xrow = x + ((size_t)(t0 + (rr >> 3)) * BATCH +
                                     8 * x_ + (rr & 7)) * DIN;
            #pragma unroll
            for (int ks = 0; ks < 16; ++ks) {
                const bf16v8 axv = cvt8(xrow + ks * 32 + rgrp * 8);
                const int gsw = ((ks * 4 + rgrp) ^ c7) << 3;
                const bf16v8 b0 = *(const bf16v8*)(wi_lds + (col) * 512 + gsw);
                const bf16v8 b1 = *(const bf16v8*)(wi_lds + (16 + col) * 512 + gsw);
                const bf16v8 b2 = *(const bf16v8*)(wi_lds + (32 + col) * 512 + gsw);
                const bf16v8 b3 = *(const bf16v8*)(wi_lds + (48 + col) * 512 + gsw);
                za0 = __builtin_amdgcn_mfma_f32_16x16x32_bf16(axv, b0, za0, 0, 0, 0);
                za1 = __builtin_amdgcn_mfma_f32_16x16x32_bf16(axv, b1, za1, 0, 0, 0);
                za2 = __builtin_amdgcn_mfma_f32_16x16x32_bf16(axv, b2, za2, 0, 0, 0);
                za3 = __builtin_amdgcn_mfma_f32_16x16x32_bf16(axv, b3, za3, 0, 0, 0);
            }
            #pragma unroll
            for (int r = 0; r < 4; ++r) {
                const int zr = (wv * 16 + rgrp * 4 + r) * ZST;
                zxb[zr + col]      = za0[r] + bvA[0];
                zxb[zr + 16 + col] = za1[r] + bvA[1];
                zxb[zr + 32 + col] = za2[r] + bvA[2];
                zxb[zr + 48 + col] = za3[r] + bvA[3];
            }
        }
        __syncthreads();

        // ---- phase B: recurrence ----
        for (int tt = 0; tt < TC; ++tt) {
            const int t = t0 + tt;

            // poll group flags >= t+1: fence-free L2-executing +0 RMW,
            // lanes<32 only (one RMW per line per block per iter). No sleep.
            if (wv == 0 && !abortf) {
                const unsigned int tgt = (unsigned int)t + 1u;
                unsigned int* fp = &flags[(x_ * 32 + (lane & 31)) * 16];
                int guard = 0;
                while (true) {
                    unsigned int v = 0xffffffffu;
                    if (lane < 32)
                        v = __hip_atomic_fetch_add(fp, zu, __ATOMIC_RELAXED,
                                                   __HIP_MEMORY_SCOPE_WORKGROUP);
                    if (__all(v >= tgt)) break;
                    if (++guard > (1 << 22)) { abortf = 1; break; }
                }
            }
            __syncthreads();

            // stage h_t (buf t&1) -> h_lds: one fence (L1 inv) + PLAIN loads
            {
                __builtin_amdgcn_fence(__ATOMIC_ACQUIRE, "agent");
                const int row = tid >> 5, ks2 = (tid >> 1) & 15, rg0 = (tid & 1) * 2;
                const unsigned long long* src = (const unsigned long long*)
                    (hglob + (((t & 1) * 8 + x_) * 8 + row) * 512)
                    + (ks2 * 8 + rg0 * 2);
                const unsigned long long q0 = src[0];
                const unsigned long long q1 = src[1];
                const unsigned long long q2 = src[2];
                const unsigned long long q3 = src[3];
                const int base = row * 512 + ks2 * 32;
                unsigned long long* d0 = (unsigned long long*)
                    (h_lds + base + ((rg0 ^ (row & 3)) << 3));
                d0[0] = q0; d0[1] = q1;
                unsigned long long* d1 = (unsigned long long*)
                    (h_lds + base + (((rg0 + 1) ^ (row & 3)) << 3));
                d1[0] = q2; d1[1] = q3;
            }
            __syncthreads();

            // z = zxb(+bias) + h @ Wh
            f32x4 accA, accB = {0, 0, 0, 0};
            {
                const int zr = (tt * 8 + (rgrp & 1) * 4) * ZST + wv * 16 + col;
                accA[0] = zxb[zr];           accA[1] = zxb[zr + ZST];
                accA[2] = zxb[zr + 2 * ZST]; accA[3] = zxb[zr + 3 * ZST];
            }
            const int abase = (col & 7) * 512 + ((rgrp ^ c3) << 3);
            #pragma unroll
            for (int ks = 0; ks < 16; ks += 2) {
                const bf16v8 a0 = *(const bf16v8*)(h_lds + abase + ks * 32);
                const bf16v8 a1 = *(const bf16v8*)(h_lds + abase + ks * 32 + 32);
                accA = __builtin_amdgcn_mfma_f32_16x16x32_bf16(a0, whf[ks],     accA, 0, 0, 0);
                accB = __builtin_amdgcn_mfma_f32_16x16x32_bf16(a1, whf[ks + 1], accB, 0, 0, 0);
            }

            float z[4], zf[4], zg[4], zo[4];
            #pragma unroll
            for (int r = 0; r < 4; ++r) z[r] = accA[r] + accB[r];
            #pragma unroll
            for (int r = 0; r < 4; ++r) {
                zf[r] = __shfl_xor(z[r], 4);    // f gate
                zg[r] = __shfl_xor(z[r], 8);    // g gate
                zo[r] = __shfl_xor(z[r], 12);   // o gate
            }

            if (act) {
                #pragma unroll
                for (int r = 0; r < 4; ++r) {
                    const float ig = sigm(z[r]);
                    const float fg = sigm(zf[r]);
                    const float gg = ftanh(zg[r]);
                    const float og = sigm(zo[r]);
                    const float cn = fg * cv[r] + ig * gg;
                    cv[r] = cn;
                    const float hn = og * ftanh(cn);
                    const int row = rgrp * 4 + r;
                    hglob[((((t + 1) & 1) * 8 + x_) * 8 + row) * 512 + hcol] =
                        f2bfbits(hn);                          // plain, write-through
                    ys_lds[(tt * 8 + row) * 16 + 4 * wv + col] = hn;
                    if (t == SEQ - 1) {
                        out[(size_t)(8 * x_ + row) * HID + hcol] = cn;                    // cT
                        out[(size_t)BATCH * HID + (size_t)(8 * x_ + row) * HID + hcol] = hn; // hT
                    }
                }
            }
            // drain ALL waves' h stores to L2, then publish via L2-executing
            // exchange (can't linger in a store buffer) + drain the exchange.
            asm volatile("s_waitcnt vmcnt(0)" ::: "memory");
            __syncthreads();
            if (tid == 0) {
                (void)__hip_atomic_exchange(&flags[(x_ * 32 + s_) * 16],
                                            (unsigned int)t + 2u,
                                            __ATOMIC_RELAXED,
                                            __HIP_MEMORY_SCOPE_WORKGROUP);
                asm volatile("s_waitcnt vmcnt(0)" ::: "memory");
            }
        }
    }

    // ---- final ys flush ----
    __syncthreads();
    {
        const int ft = tid >> 5, fr = (tid >> 2) & 7, fc = (tid & 3) * 4;
        const float4 v = *(const float4*)(ys_lds + (ft * 8 + fr) * 16 + fc);
        *(float4*)(out + 2 * (size_t)BATCH * HID +
                   ((size_t)(SEQ - TC + ft) * BATCH + 8 * x_ + fr) * HID +
                   s_ * 16 + fc) = v;
    }
}

extern "C" void kernel_launch(void* const* d_in, const int* in_sizes, int n_in,
                              void* d_out, int out_size, void* d_ws, size_t ws_size,
                              hipStream_t stream) {
    const float* x  = (const float*)d_in[0];
    const float* c0 = (const float*)d_in[1];
    const float* h0 = (const float*)d_in[2];
    const float* Wi = (const float*)d_in[3];
    const float* Wh = (const float*)d_in[4];
    const float* b  = (const float*)d_in[5];
    float* out = (float*)d_out;

    // ws: [0,16K) flags | [16K,32K) MALL rendezvous | [32K,+512) claim
    //     [36864, +128K) h double buffer [2][8 xcd][8 row][512] bf16
    char* wsb = (char*)d_ws;
    unsigned int* flags   = (unsigned int*)wsb;
    unsigned int* mall    = (unsigned int*)(wsb + 16384);
    unsigned int* claim   = (unsigned int*)(wsb + 32768);
    unsigned short* hglob = (unsigned short*)(wsb + 36864);

    (void)hipMemsetAsync(wsb, 0, 33280, stream);   // flags + mall + claim

    void* args[] = { (void*)&x, (void*)&c0, (void*)&h0, (void*)&Wi,
                     (void*)&Wh, (void*)&b, (void*)&out, (void*)&flags,
                     (void*)&mall, (void*)&claim, (void*)&hglob };
    (void)hipLaunchCooperativeKernel((void*)lstm_v12, dim3(NBLK), dim3(NT),
                                     args, 0, stream);
}